// Round 6
// baseline (161.971 us; speedup 1.0000x reference)
//
#include <hip/hip_runtime.h>
#include <math.h>

#define L_TOT 393216
#define L_D4  98304
#define NPORT 32
#define NPEAK 12
#define NOFF  21
#define NCAND 252            // NPEAK * NOFF
#define SLICES 8
#define STRIDE (SLICES * 256)   // 2048
#define NITER  (L_TOT / STRIDE) // 192
#define NNOISE 512
#define HALF_ELEMS 12582912ull   // 32 * 393216 (real plane size in fp32 elems)

// Scratch in module __device__ globals; every word unconditionally rewritten
// each call (stream-ordered: search/noise -> select -> fused).
__device__ double g_spart[NCAND * SLICES * 2];  // per-block DFT partial sums
__device__ double g_npart[NNOISE];              // per-block noise partials
__device__ int    g_prm[96];                    // T[0..32) | ideal[32..64) | m mod L [64..96)
__device__ float  g_scale[1];                   // 1/(1+noise_power)

__device__ __forceinline__ void interp_coords(int n, int* j0, float* f) {
  float x = ((float)n - 1.5f) * 0.25f;          // exact in fp32 (n < 2^19)
  if (x <= 0.f)                    { *j0 = 0;        *f = 0.f; }
  else if (x >= (float)(L_D4 - 1)) { *j0 = L_D4 - 2; *f = 1.f; }
  else { int jj = (int)x; *j0 = jj; *f = x - (float)jj; }
}

__global__ __launch_bounds__(256) void search_kernel(
    const float* __restrict__ lsr, const float* __restrict__ lsi) {
  int c  = blockIdx.x >> 3;                     // candidate
  int sl = blockIdx.x & 7;                      // slice
  int p = c / NOFF, d = c - p * NOFF;
  long long nc = (long long)p * (L_TOT / NPEAK) + (d - 10);
  if (nc < 0) nc += L_TOT;
  int k = sl * 256 + threadIdx.x;
  unsigned r    = (unsigned)(((long long)nc * k) % L_TOT);
  unsigned step = (unsigned)(((long long)nc * STRIDE) % L_TOT);
  const float w = (float)(2.0 * M_PI / (double)L_TOT);
  float er, ei, dr, di;
  __sincosf(w * (float)r,    &ei, &er);         // sin, cos
  __sincosf(w * (float)step, &di, &dr);
  double sr = 0.0, si = 0.0;
  for (int it = 0; it < NITER; ++it) {
    float a = lsr[k], b = lsi[k];
    sr += (double)(a * er - b * ei);            // ls[k] * e^{+i 2pi k nc / L}
    si += (double)(a * ei + b * er);
    float nr = er * dr - ei * di;               // rotate phasor by step
    float ni = er * di + ei * dr;
    er = nr; ei = ni;
    k += STRIDE;
  }
  __shared__ double smr[256], smi[256];
  smr[threadIdx.x] = sr; smi[threadIdx.x] = si;
  __syncthreads();
  for (int t = 128; t > 0; t >>= 1) {
    if (threadIdx.x < t) {
      smr[threadIdx.x] += smr[threadIdx.x + t];
      smi[threadIdx.x] += smi[threadIdx.x + t];
    }
    __syncthreads();
  }
  if (threadIdx.x == 0) {
    g_spart[2 * blockIdx.x]     = smr[0];
    g_spart[2 * blockIdx.x + 1] = smi[0];
  }
}

__global__ __launch_bounds__(256) void noise_kernel(
    const float* __restrict__ lsr, const float* __restrict__ lsi) {
  double acc = 0.0;
  for (int i = blockIdx.x * 256 + threadIdx.x; i < L_TOT - 1; i += NNOISE * 256) {
    float dr = lsr[i + 1] - lsr[i];
    float di = lsi[i + 1] - lsi[i];
    acc += (double)(dr * dr + di * di);
  }
  __shared__ double sm[256];
  sm[threadIdx.x] = acc;
  __syncthreads();
  for (int t = 128; t > 0; t >>= 1) {
    if (threadIdx.x < t) sm[threadIdx.x] += sm[threadIdx.x + t];
    __syncthreads();
  }
  if (threadIdx.x == 0) g_npart[blockIdx.x] = sm[0];
}

__global__ __launch_bounds__(256) void select_kernel(
    const int* __restrict__ shifts) {
  __shared__ double hmag[NCAND];
  __shared__ double nred[256];
  int tid = threadIdx.x;
  if (tid < NCAND) {
    double sr = 0.0, si = 0.0;
    for (int sl = 0; sl < SLICES; ++sl) {
      sr += g_spart[(tid * SLICES + sl) * 2];
      si += g_spart[(tid * SLICES + sl) * 2 + 1];
    }
    hmag[tid] = sr * sr + si * si;
  }
  nred[tid] = g_npart[tid] + g_npart[tid + 256];
  __syncthreads();
  for (int t = 128; t > 0; t >>= 1) {
    if (tid < t) nred[tid] += nred[tid + t];
    __syncthreads();
  }
  if (tid < NPORT) {
    int s = shifts[tid];
    int p = (NPEAK - (s % NPEAK)) % NPEAK;      // defensive mod
    int ideal = p * (L_TOT / NPEAK);
    double best = -1.0; int bd = 0;
    for (int d = 0; d < NOFF; ++d) {            // first-occurrence argmax
      double v = hmag[p * NOFF + d];
      if (v > best) { best = v; bd = d; }
    }
    int T = bd - 10;
    long long m = (long long)T + ideal;
    long long mm = m % L_TOT; if (mm < 0) mm += L_TOT;
    g_prm[tid]      = T;
    g_prm[32 + tid] = ideal;
    g_prm[64 + tid] = (int)mm;
  }
  if (tid == 0) {
    double npow = nred[0] / (double)(L_TOT - 1) * 0.5;
    g_scale[0] = (float)(1.0 / (1.0 + npow));
  }
}

// One thread per output sample n; block covers 256 consecutive n.
// Stages ls tile + havg tile (32 ports x 66 interp points) in LDS, then
// computes residual reconstruction and all 32 port outputs.
// OUTPUT: fp32 PLANAR — out[u*L+n] = real, out[HALF_ELEMS + u*L+n] = imag.
__global__ __launch_bounds__(256) void fused_kernel(
    const float* __restrict__ lsr, const float* __restrict__ lsi,
    float* __restrict__ out, unsigned long long out_elems) {
  __shared__ float2   sh_ls[264];
  __shared__ float2   sh[NPORT][66];
  __shared__ unsigned sh_base[NPORT][66];
  __shared__ int      sm_m[NPORT], sm_T[NPORT];
  __shared__ float    sm_scale;

  const float w = (float)(2.0 * M_PI / (double)L_TOT);
  int tid = threadIdx.x;
  int N0 = blockIdx.x * 256;
  int JBASE; float fd;
  interp_coords(N0, &JBASE, &fd);               // block-uniform (min j0 in block)
  int K0 = 4 * JBASE;

  if (tid < NPORT) { sm_m[tid] = g_prm[64 + tid]; sm_T[tid] = g_prm[tid]; }
  if (tid == 0) sm_scale = g_scale[0];
  for (int i = tid; i < 264; i += 256) {
    int k = K0 + i; if (k > L_TOT - 1) k = L_TOT - 1;
    sh_ls[i] = make_float2(lsr[k], lsi[k]);
  }
  __syncthreads();

  // stage havg tile: havg[u][j] = 0.25 * sum_{t<4} ls[4j+t] * e^{+i w ((m*(4j+t)) mod L)}
  for (int e = tid; e < NPORT * 66; e += 256) {
    int u = e / 66, jj = e - u * 66;
    int j = JBASE + jj; if (j > L_D4 - 1) j = L_D4 - 1;
    int k0 = 4 * j;
    unsigned mm = (unsigned)sm_m[u];
    unsigned base = (unsigned)(((unsigned long long)mm * (unsigned)k0) % L_TOT);
    sh_base[u][jj] = base;
    int kk = k0 - K0;
    float sr = 0.f, si = 0.f;
    unsigned r = base;
#pragma unroll
    for (int t = 0; t < 4; ++t) {
      float s, cs; __sincosf(w * (float)r, &s, &cs);
      float2 v = sh_ls[kk + t];
      sr += v.x * cs - v.y * s;
      si += v.x * s + v.y * cs;
      r += mm; if (r >= L_TOT) r -= L_TOT;
    }
    sh[u][jj] = make_float2(0.25f * sr, 0.25f * si);
  }
  __syncthreads();

  int n = N0 + tid;
  int j0; float f;
  interp_coords(n, &j0, &f);
  int jj0 = j0 - JBASE;                          // in [0, 64]
  unsigned dn = (unsigned)(n - 4 * j0);          // in [0, 7]
  float2 lsn = sh_ls[n - K0];

  // pass 1: h_recon = sum_u h_interp * conj(ph_m)
  float rcr = 0.f, rci = 0.f;
  for (int u = 0; u < NPORT; ++u) {
    unsigned mm = (unsigned)sm_m[u];
    unsigned rn = (sh_base[u][jj0] + dn * mm) % L_TOT;
    float2 y0 = sh[u][jj0], y1 = sh[u][jj0 + 1];
    float hr = y0.x + f * (y1.x - y0.x);
    float hi = y0.y + f * (y1.y - y0.y);
    float s, cs; __sincosf(w * (float)rn, &s, &cs);
    rcr += hr * cs + hi * s;
    rci += hi * cs - hr * s;
  }
  float resr = lsn.x - rcr, resi = lsn.y - rci;
  float scl = sm_scale;

  // pass 2: out[u][n] = scale * (h_interp*conj(ph_T) + residual*e^{i w (ideal*n mod L)})
  for (int u = 0; u < NPORT; ++u) {
    unsigned mm = (unsigned)sm_m[u];
    unsigned rn = (sh_base[u][jj0] + dn * mm) % L_TOT;
    float2 y0 = sh[u][jj0], y1 = sh[u][jj0 + 1];
    float hr = y0.x + f * (y1.x - y0.x);
    float hi = y0.y + f * (y1.y - y0.y);
    int tt = sm_T[u];
    int rT = (int)(((long long)tt * n) % L_TOT); if (rT < 0) rT += L_TOT;
    int rI = (int)rn - rT; if (rI < 0) rI += L_TOT;   // (ideal*n) mod L
    float sT, cT; __sincosf(w * (float)rT, &sT, &cT);
    float sI, cI; __sincosf(w * (float)rI, &sI, &cI);
    float orr = hr * cT + hi * sT + resr * cI - resi * sI;
    float oii = hi * cT - hr * sT + resr * sI + resi * cI;
    unsigned long long o = (unsigned long long)u * L_TOT + (unsigned)n;
    if (o < out_elems)                      out[o] = scl * orr;              // real plane
    if (HALF_ELEMS + o < out_elems)         out[HALF_ELEMS + o] = scl * oii; // imag plane
  }
}

extern "C" void kernel_launch(void* const* d_in, const int* in_sizes, int n_in,
                              void* d_out, int out_size, void* d_ws, size_t ws_size,
                              hipStream_t stream) {
  const float* lsr    = (const float*)d_in[0];
  const float* lsi    = (const float*)d_in[1];
  const int*   shifts = (const int*)d_in[2];
  float* out = (float*)d_out;

  if (in_sizes[0] != L_TOT || in_sizes[1] != L_TOT) return;  // defensive: never fault

  unsigned long long out_elems = (unsigned long long)(out_size > 0 ? out_size : 0);

  search_kernel<<<NCAND * SLICES, 256, 0, stream>>>(lsr, lsi);
  noise_kernel<<<NNOISE, 256, 0, stream>>>(lsr, lsi);
  select_kernel<<<1, 256, 0, stream>>>(shifts);
  fused_kernel<<<L_TOT / 256, 256, 0, stream>>>(lsr, lsi, out, out_elems);
}

// Round 7
// 130.462 us; speedup vs baseline: 1.2415x; 1.2415x over previous
//
#include <hip/hip_runtime.h>
#include <math.h>

#define L_TOT 393216
#define L_D4  98304
#define NPORT 32
#define NPEAK 12
#define NOFF  21
#define NCAND 252              // NPEAK * NOFF
#define TILE  1536
#define NBLK  (L_TOT / TILE)   // 256
#define HALF_ELEMS 12582912ull // 32 * 393216 (real plane in fp32 elems)

// Scratch in module __device__ globals; every word unconditionally rewritten
// each call (stream-ordered: search -> reduce -> select -> fused).
__device__ float2 g_F[NCAND * NBLK];   // F[r*21+dd][block]  (516 KB)
__device__ double g_npart[NBLK];       // per-block noise partials
__device__ double g_hmag[NCAND];       // |S(p,dd)|^2
__device__ int    g_prm[96];           // T[0..32) | p[32..64) | (unused)
__device__ float  g_scale[1];          // 1/(1+noise_power)

__constant__ double c_cos12[12] = {1.0, 0.8660254037844387, 0.5, 0.0, -0.5,
  -0.8660254037844387, -1.0, -0.8660254037844387, -0.5, 0.0, 0.5, 0.8660254037844387};
__constant__ double c_sin12[12] = {0.0, 0.5, 0.8660254037844387, 1.0,
  0.8660254037844387, 0.5, 0.0, -0.5, -0.8660254037844387, -1.0,
  -0.8660254037844387, -0.5};

__device__ __forceinline__ void interp_coords(int n, int* j0, float* f) {
  float x = ((float)n - 1.5f) * 0.25f;          // exact in fp32 (n < 2^19)
  if (x <= 0.f)                    { *j0 = 0;        *f = 0.f; }
  else if (x >= (float)(L_D4 - 1)) { *j0 = L_D4 - 2; *f = 1.f; }
  else { int jj = (int)x; *j0 = jj; *f = x - (float)jj; }
}

// z^|T| via bit decomposition (T wave-uniform), conj if T<0.
__device__ __forceinline__ float2 zpow(float2 z, float2 z2, float2 z4, float2 z8, int T) {
  int t = T < 0 ? -T : T;
  float cr = 1.f, ci = 0.f;
  if (t & 1) { cr = z.x; ci = z.y; }
  if (t & 2) { float a = cr*z2.x - ci*z2.y, b = cr*z2.y + ci*z2.x; cr = a; ci = b; }
  if (t & 4) { float a = cr*z4.x - ci*z4.y, b = cr*z4.y + ci*z4.x; cr = a; ci = b; }
  if (t & 8) { float a = cr*z8.x - ci*z8.y, b = cr*z8.y + ci*z8.x; cr = a; ci = b; }
  if (T < 0) ci = -ci;
  return make_float2(cr, ci);
}

// F[r][dd] partial sums per tile + noise partials. Each sample touched once.
__global__ __launch_bounds__(256) void search_kernel(
    const float* __restrict__ lsr, const float* __restrict__ lsi) {
  __shared__ float2 sh_ls[TILE + 1];
  __shared__ float2 sh_z[TILE];
  __shared__ float2 sh_red[NCAND * NOFF];      // 252*21 float2 = 42.3 KB (reused)
  const float w = (float)(2.0 * M_PI / (double)L_TOT);
  int tid = threadIdx.x;
  int KB = blockIdx.x * TILE;
  for (int i = tid; i < TILE + 1; i += 256) {
    int k = KB + i; if (k > L_TOT - 1) k = L_TOT - 1;
    sh_ls[i] = make_float2(lsr[k], lsi[k]);
  }
  for (int i = tid; i < TILE; i += 256) {
    float s, c; __sincosf(w * (float)(KB + i), &s, &c);
    sh_z[i] = make_float2(c, s);
  }
  __syncthreads();

  if (tid < NCAND) {
    int r = tid % 12, lane = tid / 12;         // lane in [0,21)
    float accr[NOFF], acci[NOFF];
#pragma unroll
    for (int d = 0; d < NOFF; ++d) { accr[d] = 0.f; acci[d] = 0.f; }
    for (int q = lane; q < TILE / 12; q += 21) {
      int kl = 12 * q + r;
      float2 y = sh_ls[kl];
      float2 z = sh_z[kl];
      accr[10] += y.x; acci[10] += y.y;        // delta = 0
      float cpr = y.x, cpi = y.y, cmr = y.x, cmi = y.y;
#pragma unroll
      for (int d = 1; d <= 10; ++d) {
        float tr = cpr*z.x - cpi*z.y, ti = cpr*z.y + cpi*z.x; cpr = tr; cpi = ti;
        accr[10 + d] += cpr; acci[10 + d] += cpi;          // * z^{+d}
        tr = cmr*z.x + cmi*z.y; ti = cmi*z.x - cmr*z.y; cmr = tr; cmi = ti;
        accr[10 - d] += cmr; acci[10 - d] += cmi;          // * z^{-d}
      }
    }
#pragma unroll
    for (int d = 0; d < NOFF; ++d)
      sh_red[tid * NOFF + d] = make_float2(accr[d], acci[d]);
  }
  // noise partial from the same tile (pairs i,i+1)
  double nacc = 0.0;
  int top = (KB + TILE <= L_TOT - 1) ? TILE : (L_TOT - 1 - KB);
  for (int i = tid; i < top; i += 256) {
    float2 a = sh_ls[i], b = sh_ls[i + 1];
    float dr = b.x - a.x, di = b.y - a.y;
    nacc += (double)(dr * dr + di * di);
  }
  __syncthreads();
  if (tid < NCAND) {                           // reduce 21 lanes -> F[r][dd]
    int r = tid / NOFF, dd = tid - r * NOFF;
    float fr = 0.f, fi = 0.f;
    for (int lane = 0; lane < 21; ++lane) {
      float2 v = sh_red[(lane * 12 + r) * NOFF + dd];
      fr += v.x; fi += v.y;
    }
    g_F[(r * NOFF + dd) * NBLK + blockIdx.x] = make_float2(fr, fi);
  }
  __syncthreads();                             // before reusing sh_red
  double* nb = (double*)sh_red;
  nb[tid] = nacc;
  __syncthreads();
  for (int t = 128; t > 0; t >>= 1) {
    if (tid < t) nb[tid] += nb[tid + t];
    __syncthreads();
  }
  if (tid == 0) g_npart[blockIdx.x] = nb[0];
}

// One block per candidate (p,dd): S = sum_r tbl12[p*r] * sum_b F[r][dd][b], f64.
__global__ __launch_bounds__(256) void reduce_kernel() {
  int c = blockIdx.x;
  int p = c / NOFF, dd = c - p * NOFF;
  int b = threadIdx.x;                         // NBLK == 256
  double sr = 0.0, si = 0.0;
  for (int r = 0; r < 12; ++r) {
    float2 v = g_F[(r * NOFF + dd) * NBLK + b];
    int idx = (p * r) % 12;
    double tr = c_cos12[idx], ti = c_sin12[idx];
    sr += tr * (double)v.x - ti * (double)v.y;
    si += tr * (double)v.y + ti * (double)v.x;
  }
  __shared__ double s0[256], s1[256];
  s0[b] = sr; s1[b] = si;
  __syncthreads();
  for (int t = 128; t > 0; t >>= 1) {
    if (b < t) { s0[b] += s0[b + t]; s1[b] += s1[b + t]; }
    __syncthreads();
  }
  if (b == 0) g_hmag[c] = s0[0] * s0[0] + s1[0] * s1[0];
}

__global__ __launch_bounds__(256) void select_kernel(
    const int* __restrict__ shifts) {
  __shared__ double hmag[NCAND];
  __shared__ double nred[256];
  int tid = threadIdx.x;
  if (tid < NCAND) hmag[tid] = g_hmag[tid];
  nred[tid] = g_npart[tid];
  __syncthreads();
  for (int t = 128; t > 0; t >>= 1) {
    if (tid < t) nred[tid] += nred[tid + t];
    __syncthreads();
  }
  if (tid < NPORT) {
    int s = shifts[tid];
    int p = (NPEAK - (s % NPEAK)) % NPEAK;
    double best = -1.0; int bd = 0;
    for (int d = 0; d < NOFF; ++d) {           // first-occurrence argmax
      double v = hmag[p * NOFF + d];
      if (v > best) { best = v; bd = d; }
    }
    g_prm[tid]      = bd - 10;                 // T
    g_prm[32 + tid] = p;                       // peak index (ideal = p*L/12)
  }
  if (tid == 0) {
    double npow = nred[0] / (double)(L_TOT - 1) * 0.5;
    g_scale[0] = (float)(1.0 / (1.0 + npow));
  }
}

// One thread per output sample n. All phasors built from z_n = e^{2pi i n/L}
// (one sincos per staged sample) + a 144-entry 12th-root table:
//   ph_I = tbl[p][n%12], ph_T = z^T (|T|<=10), ph_m = tbl*z^T.
// out[u][n] = scl*(h_interp*conj(ph_T) + res*tbl), planar fp32.
__global__ __launch_bounds__(256) void fused_kernel(
    const float* __restrict__ lsr, const float* __restrict__ lsi,
    float* __restrict__ out, unsigned long long out_elems) {
  __shared__ float2 sh_ls[264];
  __shared__ float2 sh_z[264];
  __shared__ float2 sh_h[NPORT][66];
  __shared__ float2 sh_tbl[144];
  __shared__ int    sm_T[NPORT], sm_p[NPORT];
  __shared__ float  sm_scale;

  const float w = (float)(2.0 * M_PI / (double)L_TOT);
  int tid = threadIdx.x;
  int N0 = blockIdx.x * 256;
  int JBASE; float fd;
  interp_coords(N0, &JBASE, &fd);
  int K0 = 4 * JBASE;

  if (tid < NPORT) { sm_T[tid] = g_prm[tid]; sm_p[tid] = g_prm[32 + tid]; }
  if (tid == 0) sm_scale = g_scale[0];
  if (tid < 144) {
    int p = tid / 12, r = tid - p * 12;
    int idx = (p * r) % 12;
    float s, c; __sincosf((float)(2.0 * M_PI / 12.0) * (float)idx, &s, &c);
    sh_tbl[tid] = make_float2(c, s);
  }
  for (int i = tid; i < 264; i += 256) {
    int k = K0 + i; if (k > L_TOT - 1) k = L_TOT - 1;
    sh_ls[i] = make_float2(lsr[k], lsi[k]);
    float s, c; __sincosf(w * (float)k, &s, &c);
    sh_z[i] = make_float2(c, s);
  }
  __syncthreads();

  // havg tile: h[u][jj] = 0.25 * sum_{t<4} ls[k] * tbl[p][k%12] * z_k^T
  for (int e = tid; e < NPORT * 66; e += 256) {
    int u = e / 66, jj = e - u * 66;
    int j = JBASE + jj; if (j > L_D4 - 1) j = L_D4 - 1;
    int k0 = 4 * j, kk = k0 - K0;
    int T = sm_T[u], p = sm_p[u];
    int r0 = k0 % 12;
    float sr = 0.f, si = 0.f;
#pragma unroll
    for (int t = 0; t < 4; ++t) {
      float2 z = sh_z[kk + t];
      float2 z2 = make_float2(z.x*z.x - z.y*z.y, 2.f*z.x*z.y);
      float2 z4 = make_float2(z2.x*z2.x - z2.y*z2.y, 2.f*z2.x*z2.y);
      float2 z8 = make_float2(z4.x*z4.x - z4.y*z4.y, 2.f*z4.x*z4.y);
      float2 zT = zpow(z, z2, z4, z8, T);
      int rr = r0 + t; if (rr >= 12) rr -= 12;
      float2 tb = sh_tbl[p * 12 + rr];
      float phr = tb.x*zT.x - tb.y*zT.y, phi = tb.x*zT.y + tb.y*zT.x;
      float2 v = sh_ls[kk + t];
      sr += v.x*phr - v.y*phi;
      si += v.x*phi + v.y*phr;
    }
    sh_h[u][jj] = make_float2(0.25f * sr, 0.25f * si);
  }
  __syncthreads();

  int n = N0 + tid;
  int j0; float f;
  interp_coords(n, &j0, &f);
  int jj0 = j0 - JBASE;
  int r12 = n % 12;
  float2 lsn = sh_ls[n - K0];
  float2 zn = sh_z[n - K0];
  float2 z2 = make_float2(zn.x*zn.x - zn.y*zn.y, 2.f*zn.x*zn.y);
  float2 z4 = make_float2(z2.x*z2.x - z2.y*z2.y, 2.f*z2.x*z2.y);
  float2 z8 = make_float2(z4.x*z4.x - z4.y*z4.y, 2.f*z4.x*z4.y);

  // pass 1: recon = sum_u h_interp * conj(ph_m), ph_m = tbl*z^T
  float rcr = 0.f, rci = 0.f;
#pragma unroll
  for (int u = 0; u < NPORT; ++u) {
    float2 zT = zpow(zn, z2, z4, z8, sm_T[u]);
    float2 tb = sh_tbl[sm_p[u] * 12 + r12];
    float phr = tb.x*zT.x - tb.y*zT.y, phi = tb.x*zT.y + tb.y*zT.x;
    float2 y0 = sh_h[u][jj0], y1 = sh_h[u][jj0 + 1];
    float hr = y0.x + f * (y1.x - y0.x);
    float hi = y0.y + f * (y1.y - y0.y);
    rcr += hr * phr + hi * phi;
    rci += hi * phr - hr * phi;
  }
  float resr = lsn.x - rcr, resi = lsn.y - rci;
  float scl = sm_scale;

  // pass 2: out = scl*(h*conj(z^T) + res*tbl), planar fp32
#pragma unroll
  for (int u = 0; u < NPORT; ++u) {
    float2 zT = zpow(zn, z2, z4, z8, sm_T[u]);
    float2 tb = sh_tbl[sm_p[u] * 12 + r12];
    float2 y0 = sh_h[u][jj0], y1 = sh_h[u][jj0 + 1];
    float hr = y0.x + f * (y1.x - y0.x);
    float hi = y0.y + f * (y1.y - y0.y);
    float orr = hr*zT.x + hi*zT.y + resr*tb.x - resi*tb.y;
    float oii = hi*zT.x - hr*zT.y + resr*tb.y + resi*tb.x;
    unsigned long long o = (unsigned long long)u * L_TOT + (unsigned)n;
    if (o < out_elems)              out[o] = scl * orr;
    if (HALF_ELEMS + o < out_elems) out[HALF_ELEMS + o] = scl * oii;
  }
}

extern "C" void kernel_launch(void* const* d_in, const int* in_sizes, int n_in,
                              void* d_out, int out_size, void* d_ws, size_t ws_size,
                              hipStream_t stream) {
  const float* lsr    = (const float*)d_in[0];
  const float* lsi    = (const float*)d_in[1];
  const int*   shifts = (const int*)d_in[2];
  float* out = (float*)d_out;

  if (in_sizes[0] != L_TOT || in_sizes[1] != L_TOT) return;  // defensive: never fault

  unsigned long long out_elems = (unsigned long long)(out_size > 0 ? out_size : 0);

  search_kernel<<<NBLK, 256, 0, stream>>>(lsr, lsi);
  reduce_kernel<<<NCAND, 256, 0, stream>>>();
  select_kernel<<<1, 256, 0, stream>>>(shifts);
  fused_kernel<<<L_TOT / 256, 256, 0, stream>>>(lsr, lsi, out, out_elems);
}

// Round 8
// 121.722 us; speedup vs baseline: 1.3307x; 1.0718x over previous
//
#include <hip/hip_runtime.h>
#include <math.h>

#define L_TOT 393216
#define L_D4  98304
#define NPORT 32
#define NPEAK 12
#define NOFF  21
#define NCAND 252              // NPEAK * NOFF
#define TILE  1536
#define NBLK  (L_TOT / TILE)   // 256
#define HALF_ELEMS 12582912ull // 32 * 393216 (real plane in fp32 elems)

// Scratch in module __device__ globals; every word unconditionally rewritten
// each call (stream-ordered: search -> select -> fused).
__device__ float2 g_F[NBLK * NCAND];   // [block][cand]  (coalesced both sides)
__device__ double g_npart[NBLK];       // per-block noise partials
__device__ int    g_prm[96];           // T[0..32) | p[32..64) | m mod L [64..96)
__device__ float  g_scale[1];          // 1/(1+noise_power)

__constant__ double c_cos12[12] = {1.0, 0.8660254037844387, 0.5, 0.0, -0.5,
  -0.8660254037844387, -1.0, -0.8660254037844387, -0.5, 0.0, 0.5, 0.8660254037844387};
__constant__ double c_sin12[12] = {0.0, 0.5, 0.8660254037844387, 1.0,
  0.8660254037844387, 0.5, 0.0, -0.5, -0.8660254037844387, -1.0,
  -0.8660254037844387, -0.5};

__device__ __forceinline__ void interp_coords(int n, int* j0, float* f) {
  float x = ((float)n - 1.5f) * 0.25f;          // exact in fp32 (n < 2^19)
  if (x <= 0.f)                    { *j0 = 0;        *f = 0.f; }
  else if (x >= (float)(L_D4 - 1)) { *j0 = L_D4 - 2; *f = 1.f; }
  else { int jj = (int)x; *j0 = jj; *f = x - (float)jj; }
}

// z^T with SCALAR T (pass readfirstlane'd value) -> s_cbranch, ~3 cmults max.
__device__ __forceinline__ float2 zpowS(float2 z, float2 z2, float2 z4, float2 z8, int T) {
  int t = T < 0 ? -T : T;
  float cr = 1.f, ci = 0.f;
  if (t & 1) { cr = z.x; ci = z.y; }
  if (t & 2) { float a = cr*z2.x - ci*z2.y, b = cr*z2.y + ci*z2.x; cr = a; ci = b; }
  if (t & 4) { float a = cr*z4.x - ci*z4.y, b = cr*z4.y + ci*z4.x; cr = a; ci = b; }
  if (t & 8) { float a = cr*z8.x - ci*z8.y, b = cr*z8.y + ci*z8.x; cr = a; ci = b; }
  if (T < 0) ci = -ci;
  return make_float2(cr, ci);
}

// F[c] partial sums per tile + noise partials. Each sample touched once.
__global__ __launch_bounds__(256) void search_kernel(
    const float* __restrict__ lsr, const float* __restrict__ lsi) {
  __shared__ float2 sh_ls[TILE + 1];
  __shared__ float2 sh_z[TILE];
  __shared__ float2 sh_red[NCAND * NOFF];      // 42.3 KB (reused for noise reduce)
  const float w = (float)(2.0 * M_PI / (double)L_TOT);
  int tid = threadIdx.x;
  int KB = blockIdx.x * TILE;
  for (int i = tid; i < TILE + 1; i += 256) {
    int k = KB + i; if (k > L_TOT - 1) k = L_TOT - 1;
    sh_ls[i] = make_float2(lsr[k], lsi[k]);
  }
  for (int i = tid; i < TILE; i += 256) {
    float s, c; __sincosf(w * (float)(KB + i), &s, &c);
    sh_z[i] = make_float2(c, s);
  }
  __syncthreads();

  if (tid < NCAND) {
    int r = tid % 12, lane = tid / 12;         // lane in [0,21)
    float accr[NOFF], acci[NOFF];
#pragma unroll
    for (int d = 0; d < NOFF; ++d) { accr[d] = 0.f; acci[d] = 0.f; }
    for (int q = lane; q < TILE / 12; q += 21) {
      int kl = 12 * q + r;
      float2 y = sh_ls[kl];
      float2 z = sh_z[kl];
      accr[10] += y.x; acci[10] += y.y;        // delta = 0
      float cpr = y.x, cpi = y.y, cmr = y.x, cmi = y.y;
#pragma unroll
      for (int d = 1; d <= 10; ++d) {
        float tr = cpr*z.x - cpi*z.y, ti = cpr*z.y + cpi*z.x; cpr = tr; cpi = ti;
        accr[10 + d] += cpr; acci[10 + d] += cpi;          // * z^{+d}
        tr = cmr*z.x + cmi*z.y; ti = cmi*z.x - cmr*z.y; cmr = tr; cmi = ti;
        accr[10 - d] += cmr; acci[10 - d] += cmi;          // * z^{-d}
      }
    }
#pragma unroll
    for (int d = 0; d < NOFF; ++d)
      sh_red[tid * NOFF + d] = make_float2(accr[d], acci[d]);
  }
  double nacc = 0.0;
  int top = (KB + TILE <= L_TOT - 1) ? TILE : (L_TOT - 1 - KB);
  for (int i = tid; i < top; i += 256) {
    float2 a = sh_ls[i], b = sh_ls[i + 1];
    float dr = b.x - a.x, di = b.y - a.y;
    nacc += (double)(dr * dr + di * di);
  }
  __syncthreads();
  if (tid < NCAND) {                           // reduce 21 lanes -> F[c], c=tid
    int r = tid / NOFF, dd = tid - r * NOFF;
    float fr = 0.f, fi = 0.f;
    for (int lane = 0; lane < 21; ++lane) {
      float2 v = sh_red[(lane * 12 + r) * NOFF + dd];
      fr += v.x; fi += v.y;
    }
    g_F[blockIdx.x * NCAND + tid] = make_float2(fr, fi);
  }
  __syncthreads();                             // before reusing sh_red
  double* nb = (double*)sh_red;
  nb[tid] = nacc;
  __syncthreads();
  for (int t = 128; t > 0; t >>= 1) {
    if (tid < t) nb[tid] += nb[tid + t];
    __syncthreads();
  }
  if (tid == 0) g_npart[blockIdx.x] = nb[0];
}

// Merged reduce+select, 1 block: G[c] = sum_b F[b][c] (coalesced), then
// S(p,dd) = sum_r w12^{p r} G[r][dd], argmax per port, noise scale.
__global__ __launch_bounds__(256) void select_kernel(
    const int* __restrict__ shifts) {
  __shared__ double sGr[NCAND], sGi[NCAND];
  __shared__ double hmag[NCAND];
  __shared__ double nred[256];
  int tid = threadIdx.x;
  if (tid < NCAND) {
    double gr = 0.0, gi = 0.0;
    for (int b = 0; b < NBLK; ++b) {
      float2 v = g_F[b * NCAND + tid];
      gr += (double)v.x; gi += (double)v.y;
    }
    sGr[tid] = gr; sGi[tid] = gi;
  }
  nred[tid] = g_npart[tid];
  __syncthreads();
  if (tid < NCAND) {
    int p = tid / NOFF, dd = tid - p * NOFF;
    double sr = 0.0, si = 0.0;
    for (int r = 0; r < 12; ++r) {
      int idx = (p * r) % 12;
      double gr = sGr[r * NOFF + dd], gi = sGi[r * NOFF + dd];
      sr += c_cos12[idx] * gr - c_sin12[idx] * gi;
      si += c_cos12[idx] * gi + c_sin12[idx] * gr;
    }
    hmag[tid] = sr * sr + si * si;
  }
  __syncthreads();
  for (int t = 128; t > 0; t >>= 1) {
    if (tid < t) nred[tid] += nred[tid + t];
    __syncthreads();
  }
  if (tid < NPORT) {
    int s = shifts[tid];
    int p = (NPEAK - (s % NPEAK)) % NPEAK;
    double best = -1.0; int bd = 0;
    for (int d = 0; d < NOFF; ++d) {           // first-occurrence argmax
      double v = hmag[p * NOFF + d];
      if (v > best) { best = v; bd = d; }
    }
    int T = bd - 10;
    int m = T + p * (L_TOT / NPEAK);
    if (m < 0) m += L_TOT;
    g_prm[tid]      = T;
    g_prm[32 + tid] = p;
    g_prm[64 + tid] = m;                       // m mod L
  }
  if (tid == 0) {
    double npow = nred[0] / (double)(L_TOT - 1) * 0.5;
    g_scale[0] = (float)(1.0 / (1.0 + npow));
  }
}

// One thread per output sample n. Pass 1 caches A_u = h_interp*conj(z^T) in
// registers; pass 2: out_u = scl*(A_u + res*tbl). Planar fp32 output.
__global__ __launch_bounds__(256) void fused_kernel(
    const float* __restrict__ lsr, const float* __restrict__ lsi,
    float* __restrict__ out, unsigned long long out_elems) {
  __shared__ float2 sh_ls[264];
  __shared__ float2 sh_h[NPORT][67];           // padded: conflict-free staging writes
  __shared__ float2 sh_tbl[144];
  __shared__ float2 sh_stp[NPORT];             // e^{i w m_u}
  __shared__ int    sm_T[NPORT], sm_p[NPORT], sm_m[NPORT];
  __shared__ float  sm_scale;

  const float w = (float)(2.0 * M_PI / (double)L_TOT);
  int tid = threadIdx.x;
  int N0 = blockIdx.x * 256;
  int JBASE; float fd;
  interp_coords(N0, &JBASE, &fd);              // block-uniform (min j0 in block)
  int K0 = 4 * JBASE;

  if (tid < NPORT) {
    sm_T[tid] = g_prm[tid]; sm_p[tid] = g_prm[32 + tid];
    int m = g_prm[64 + tid]; sm_m[tid] = m;
    float s, c; __sincosf(w * (float)m, &s, &c);
    sh_stp[tid] = make_float2(c, s);
  }
  if (tid == 0) sm_scale = g_scale[0];
  if (tid < 144) {
    int p = tid / 12, r = tid - p * 12;
    int idx = (p * r) % 12;
    float s, c; __sincosf((float)(2.0 * M_PI / 12.0) * (float)idx, &s, &c);
    sh_tbl[tid] = make_float2(c, s);
  }
  for (int i = tid; i < 264; i += 256) {
    int k = K0 + i; if (k > L_TOT - 1) k = L_TOT - 1;
    sh_ls[i] = make_float2(lsr[k], lsi[k]);
  }
  __syncthreads();

  // havg tile, e = jj*32 + u (conflict-free). Phasor: 1 sincos + 3 recurrence.
  for (int e = tid; e < NPORT * 66; e += 256) {
    int u = e & 31, jj = e >> 5;
    int j = JBASE + jj; if (j > L_D4 - 1) j = L_D4 - 1;
    int k0 = 4 * j, kk = k0 - K0;
    unsigned rr = (unsigned)(((long long)sm_m[u] * k0) % L_TOT);
    float phs, phc; __sincosf(w * (float)rr, &phs, &phc);
    float2 stp = sh_stp[u];
    float sr = 0.f, si = 0.f;
#pragma unroll
    for (int t = 0; t < 4; ++t) {
      float2 v = sh_ls[kk + t];
      sr += v.x * phc - v.y * phs;
      si += v.x * phs + v.y * phc;
      float a = phc * stp.x - phs * stp.y, b = phc * stp.y + phs * stp.x;
      phc = a; phs = b;
    }
    sh_h[u][jj] = make_float2(0.25f * sr, 0.25f * si);
  }
  __syncthreads();

  int n = N0 + tid;
  int j0; float f;
  interp_coords(n, &j0, &f);
  int jj0 = j0 - JBASE;                        // in [0, 64]
  int r12 = n % 12;
  float2 lsn = sh_ls[n - K0];
  float zs, zc; __sincosf(w * (float)n, &zs, &zc);
  float2 zn = make_float2(zc, zs);
  float2 z2 = make_float2(zn.x*zn.x - zn.y*zn.y, 2.f*zn.x*zn.y);
  float2 z4 = make_float2(z2.x*z2.x - z2.y*z2.y, 2.f*z2.x*z2.y);
  float2 z8 = make_float2(z4.x*z4.x - z4.y*z4.y, 2.f*z4.x*z4.y);

  float aAr[NPORT], aAi[NPORT];
  float rcr = 0.f, rci = 0.f;
#pragma unroll
  for (int u = 0; u < NPORT; ++u) {
    int T = __builtin_amdgcn_readfirstlane(sm_T[u]);   // block-uniform -> scalar
    int p = __builtin_amdgcn_readfirstlane(sm_p[u]);
    float2 zT = zpowS(zn, z2, z4, z8, T);
    float2 tb = sh_tbl[p * 12 + r12];
    float2 y0 = sh_h[u][jj0], y1 = sh_h[u][jj0 + 1];
    float hr = y0.x + f * (y1.x - y0.x);
    float hi = y0.y + f * (y1.y - y0.y);
    float Ar = hr * zT.x + hi * zT.y;          // A = h * conj(zT)
    float Ai = hi * zT.x - hr * zT.y;
    aAr[u] = Ar; aAi[u] = Ai;
    rcr += Ar * tb.x + Ai * tb.y;              // recon += A * conj(tb)
    rci += Ai * tb.x - Ar * tb.y;
  }
  float resr = lsn.x - rcr, resi = lsn.y - rci;
  float scl = sm_scale;

  if (out_elems >= 2ull * HALF_ELEMS) {        // full-size output: unguarded
#pragma unroll
    for (int u = 0; u < NPORT; ++u) {
      int p = __builtin_amdgcn_readfirstlane(sm_p[u]);
      float2 tb = sh_tbl[p * 12 + r12];
      float orr = aAr[u] + resr * tb.x - resi * tb.y;
      float oii = aAi[u] + resr * tb.y + resi * tb.x;
      unsigned long long o = (unsigned long long)u * L_TOT + (unsigned)n;
      out[o] = scl * orr;
      out[HALF_ELEMS + o] = scl * oii;
    }
  } else {
#pragma unroll
    for (int u = 0; u < NPORT; ++u) {
      int p = __builtin_amdgcn_readfirstlane(sm_p[u]);
      float2 tb = sh_tbl[p * 12 + r12];
      float orr = aAr[u] + resr * tb.x - resi * tb.y;
      float oii = aAi[u] + resr * tb.y + resi * tb.x;
      unsigned long long o = (unsigned long long)u * L_TOT + (unsigned)n;
      if (o < out_elems)              out[o] = scl * orr;
      if (HALF_ELEMS + o < out_elems) out[HALF_ELEMS + o] = scl * oii;
    }
  }
}

extern "C" void kernel_launch(void* const* d_in, const int* in_sizes, int n_in,
                              void* d_out, int out_size, void* d_ws, size_t ws_size,
                              hipStream_t stream) {
  const float* lsr    = (const float*)d_in[0];
  const float* lsi    = (const float*)d_in[1];
  const int*   shifts = (const int*)d_in[2];
  float* out = (float*)d_out;

  if (in_sizes[0] != L_TOT || in_sizes[1] != L_TOT) return;  // defensive: never fault

  unsigned long long out_elems = (unsigned long long)(out_size > 0 ? out_size : 0);

  search_kernel<<<NBLK, 256, 0, stream>>>(lsr, lsi);
  select_kernel<<<1, 256, 0, stream>>>(shifts);
  fused_kernel<<<L_TOT / 256, 256, 0, stream>>>(lsr, lsi, out, out_elems);
}